// Round 12
// baseline (211.814 us; speedup 1.0000x reference)
//
#include <hip/hip_runtime.h>

#define N_NODES 200000
#define N_EDGES 6400000
#define IN_DIM 15
#define POS_DIM 4

#define CSHIFT 8
#define CMASK 255
#define CW 256                                      // nodes per bucket
#define NCOARSE ((N_NODES + CW - 1) >> CSHIFT)      // 782
#define CHUNK 16384                                 // edges per hist/scatter block
#define NBLK ((N_EDGES + CHUNK - 1) / CHUNK)        // 391
#define CAP 9216                                    // max bucket edges in LDS (+11 sigma)

typedef unsigned uv4 __attribute__((ext_vector_type(4)));

// ---------------- Pass A: per-node precompute ----------------
__global__ void node_prep(const float* __restrict__ x,
                          const float* __restrict__ Wlin,
                          const float* __restrict__ Wsrc,
                          const float* __restrict__ Wdst,
                          const float* __restrict__ Wpos,
                          float2* __restrict__ tabI,
                          float4* __restrict__ tabJ,
                          float2* __restrict__ pvec)
{
    int n = blockIdx.x * blockDim.x + threadIdx.x;
    if (n >= N_NODES) return;
    const float* xp = x + (long)n * IN_DIM;
    float xv[IN_DIM];
#pragma unroll
    for (int k = 0; k < IN_DIM; ++k) xv[k] = xp[k];

    float p0 = 0.f, p1 = 0.f;
#pragma unroll
    for (int k = 0; k < POS_DIM; ++k) {
        p0 += Wpos[k] * xv[k];
        p1 += Wpos[POS_DIM + k] * xv[k];
    }
    float v0 = 0.f, v1 = 0.f, as0 = 0.f, as1 = 0.f, ad0 = 0.f, ad1 = 0.f;
#pragma unroll
    for (int k = 0; k < IN_DIM; ++k) {
        float xk = xv[k];
        v0  += Wlin[k] * xk;           v1  += Wlin[IN_DIM + k] * xk;
        as0 += Wsrc[k] * xk;           as1 += Wsrc[IN_DIM + k] * xk;
        ad0 += Wdst[k] * xk;           ad1 += Wdst[IN_DIM + k] * xk;
    }
    tabI[n] = make_float2(ad0 + p0, ad1 + p1);
    tabJ[n] = make_float4(as0 + p0, as1 + p1, v0 - p0, v1 - p1);
    pvec[n] = make_float2(p0, p1);
}

// ---------------- K1: per-block bucket histogram (512 threads) --------------
__global__ void hist_kernel(const int* __restrict__ idx,
                            unsigned* __restrict__ hist)   // [NBLK][NCOARSE]
{
    __shared__ unsigned h[NCOARSE];
    for (int t = threadIdx.x; t < NCOARSE; t += blockDim.x) h[t] = 0u;
    __syncthreads();
    long s0 = (long)blockIdx.x * CHUNK;
    int end = (int)min((long)CHUNK, (long)N_EDGES - s0);   // always %2048==0
    for (int t = threadIdx.x * 4; t < end; t += 2048) {
        int4 iv = *(const int4*)(idx + s0 + t);
        atomicAdd(&h[iv.x >> CSHIFT], 1u);
        atomicAdd(&h[iv.y >> CSHIFT], 1u);
        atomicAdd(&h[iv.z >> CSHIFT], 1u);
        atomicAdd(&h[iv.w >> CSHIFT], 1u);
    }
    __syncthreads();
    for (int t = threadIdx.x; t < NCOARSE; t += blockDim.x)
        hist[(unsigned)blockIdx.x * NCOARSE + t] = h[t];
}

// ---------------- K2: exclusive scan down each bucket column ----------------
__global__ void colscan_kernel(unsigned* __restrict__ hist,
                               unsigned* __restrict__ totals)
{
    __shared__ unsigned s[512];
    int k = blockIdx.x;                      // 782 columns
    int t = threadIdx.x;                     // blockDim = 512 >= NBLK
    unsigned v = (t < NBLK) ? hist[(unsigned)t * NCOARSE + k] : 0u;
    s[t] = v;
    __syncthreads();
    for (int off = 1; off < 512; off <<= 1) {
        unsigned add = (t >= off) ? s[t - off] : 0u;
        __syncthreads();
        s[t] += add;
        __syncthreads();
    }
    if (t < NBLK) hist[(unsigned)t * NCOARSE + k] = s[t] - v;   // exclusive
    if (t == NBLK - 1) totals[k] = s[t];
}

// ---------------- K3: scan of 4-padded totals -> aligned bases (1024 wide) --
__global__ void basescan_kernel(const unsigned* __restrict__ totals,
                                unsigned* __restrict__ base)
{
    __shared__ unsigned s[1024];
    int t = threadIdx.x;                     // blockDim = 512, 2 elems/thread
    int e0 = t, e1 = t + 512;
    unsigned v0 = (e0 < NCOARSE) ? ((totals[e0] + 3u) & ~3u) : 0u;
    unsigned v1 = (e1 < NCOARSE) ? ((totals[e1] + 3u) & ~3u) : 0u;
    s[e0] = v0; s[e1] = v1;
    __syncthreads();
    for (int off = 1; off < 1024; off <<= 1) {
        unsigned a0 = (e0 >= off) ? s[e0 - off] : 0u;
        unsigned a1 = (e1 >= off) ? s[e1 - off] : 0u;
        __syncthreads();
        s[e0] += a0; s[e1] += a1;
        __syncthreads();
    }
    if (e0 < NCOARSE) base[e0] = s[e0] - v0;   // exclusive, multiple of 4
    if (e1 < NCOARSE) base[e1] = s[e1] - v1;
}

// ---------------- K4: LDS-staged scatter (512 threads, 1024-wide tables) ----
// Deterministic block-ordered placement; runs ~21 entries, address-adjacent.
__global__ void scatter_kernel(const int* __restrict__ idx,
                               const unsigned* __restrict__ hist,
                               const unsigned* __restrict__ base,
                               unsigned* __restrict__ packed)
{
    __shared__ unsigned stage[CHUNK];        // 64 KB
    __shared__ unsigned cnt[1024];           // counts -> cur
    __shared__ unsigned sc[1024];            // scan workspace
    __shared__ unsigned lloc[1025];          // exclusive local starts + sentinel
    __shared__ unsigned gdst[1024];
    int b = blockIdx.x;
    int t = threadIdx.x;                     // 512 threads (8 waves)
    long s0 = (long)b * CHUNK;
    int end = (int)min((long)CHUNK, (long)N_EDGES - s0);   // %2048==0
    cnt[t] = 0u; cnt[t + 512] = 0u;
    __syncthreads();
    // pass 1: local histogram
    for (int e = t * 4; e < end; e += 2048) {
        int4 iv = *(const int4*)(idx + s0 + e);
        atomicAdd(&cnt[iv.x >> CSHIFT], 1u);
        atomicAdd(&cnt[iv.y >> CSHIFT], 1u);
        atomicAdd(&cnt[iv.z >> CSHIFT], 1u);
        atomicAdd(&cnt[iv.w >> CSHIFT], 1u);
    }
    __syncthreads();
    // inclusive scan over 1024 (2 elems/thread Hillis-Steele, R8-proven)
    sc[t] = cnt[t]; sc[t + 512] = cnt[t + 512];
    __syncthreads();
    for (int o = 1; o < 1024; o <<= 1) {
        unsigned a0 = (t >= o) ? sc[t - o] : 0u;
        unsigned a1 = (t + 512 >= o) ? sc[t + 512 - o] : 0u;
        __syncthreads();
        sc[t] += a0; sc[t + 512] += a1;
        __syncthreads();
    }
    {
        unsigned ex0 = sc[t] - cnt[t];
        unsigned ex1 = sc[t + 512] - cnt[t + 512];
        lloc[t] = ex0; lloc[t + 512] = ex1;
        cnt[t] = ex0; cnt[t + 512] = ex1;            // cnt becomes cur
        if (t < NCOARSE) gdst[t] = base[t] + hist[(unsigned)b * NCOARSE + t];
        int u = t + 512;
        if (u < NCOARSE) gdst[u] = base[u] + hist[(unsigned)b * NCOARSE + u];
        if (t == 0) lloc[1024] = (unsigned)end;      // sentinel
    }
    __syncthreads();
    // pass 2: place into LDS stage, bucket-major
    for (int e = t * 4; e < end; e += 2048) {
        int4 iv = *(const int4*)(idx + s0 + e);
        int4 jv = *(const int4*)(idx + N_EDGES + s0 + e);
        unsigned r0 = atomicAdd(&cnt[iv.x >> CSHIFT], 1u);
        unsigned r1 = atomicAdd(&cnt[iv.y >> CSHIFT], 1u);
        unsigned r2 = atomicAdd(&cnt[iv.z >> CSHIFT], 1u);
        unsigned r3 = atomicAdd(&cnt[iv.w >> CSHIFT], 1u);
        stage[r0] = ((unsigned)jv.x << CSHIFT) | (unsigned)(iv.x & CMASK);
        stage[r1] = ((unsigned)jv.y << CSHIFT) | (unsigned)(iv.y & CMASK);
        stage[r2] = ((unsigned)jv.z << CSHIFT) | (unsigned)(iv.z & CMASK);
        stage[r3] = ((unsigned)jv.w << CSHIFT) | (unsigned)(iv.w & CMASK);
    }
    __syncthreads();
    // pass 3: dense copy-out, one wave per bucket run (8 waves)
    int wid = t >> 6, lane = t & 63;
    for (int bk = wid; bk < 1024; bk += 8) {
        unsigned st = lloc[bk];
        unsigned len = lloc[bk + 1] - st;
        if (len == 0u) continue;
        unsigned gd = gdst[bk];
        for (unsigned e = lane; e < len; e += 64u)
            packed[gd + e] = stage[st + e];
    }
}

// ---------------- K5: fused per-bucket sort + aggregate (512t, 40KB LDS) ----
// One block per 256-node bucket (grid 782 -> 4 blocks/CU capacity, full CU
// coverage). Counting-sort the bucket window into LDS node-major, then 2
// threads per node aggregate disjoint halves and combine via shfl_xor.
__global__ void bucket_agg_kernel(const unsigned* __restrict__ packed,
                                  const unsigned* __restrict__ base,
                                  const unsigned* __restrict__ totals,
                                  const float2* __restrict__ tabI,
                                  const float4* __restrict__ tabJ,
                                  const float2* __restrict__ pvec,
                                  const float* __restrict__ bpos,
                                  float2* __restrict__ out)
{
    __shared__ unsigned cache[CAP + 256];    // node-major j values (+node stagger)
    __shared__ unsigned cnt[256], sc[256], cur[256];
    int k = blockIdx.x;
    int t = threadIdx.x;                     // 512 threads
    unsigned s = base[k];
    unsigned n = min(totals[k], (unsigned)CAP);   // loud-fail clamp, never hit
    if (t < 256) cnt[t] = 0u;
    __syncthreads();
    // pass 1: histogram of low 8 bits
    for (unsigned e = 4u * t; e < n; e += 2048u) {
        uv4 p = *(const uv4*)(packed + s + e);   // 4-pad -> aligned over-read safe
        atomicAdd(&cnt[p.x & CMASK], 1u);
        if (e + 1 < n) atomicAdd(&cnt[p.y & CMASK], 1u);
        if (e + 2 < n) atomicAdd(&cnt[p.z & CMASK], 1u);
        if (e + 3 < n) atomicAdd(&cnt[p.w & CMASK], 1u);
    }
    __syncthreads();
    // inclusive scan over 256 (t<256 active, barriers uniform)
    if (t < 256) sc[t] = cnt[t];
    __syncthreads();
    for (int o = 1; o < 256; o <<= 1) {
        unsigned a = 0u;
        if (t < 256 && t >= o) a = sc[t - o];
        __syncthreads();
        if (t < 256) sc[t] += a;
        __syncthreads();
    }
    if (t < 256) cur[t] = sc[t] - cnt[t] + (unsigned)t;   // start (+stagger)
    __syncthreads();
    // pass 2: place bare j into LDS, node-major
    for (unsigned e = 4u * t; e < n; e += 2048u) {
        uv4 p = __builtin_nontemporal_load((const uv4*)(packed + s + e));
        { unsigned pos = atomicAdd(&cur[p.x & CMASK], 1u); cache[pos] = p.x >> CSHIFT; }
        if (e + 1 < n) { unsigned pos = atomicAdd(&cur[p.y & CMASK], 1u); cache[pos] = p.y >> CSHIFT; }
        if (e + 2 < n) { unsigned pos = atomicAdd(&cur[p.z & CMASK], 1u); cache[pos] = p.z >> CSHIFT; }
        if (e + 3 < n) { unsigned pos = atomicAdd(&cur[p.w & CMASK], 1u); cache[pos] = p.w >> CSHIFT; }
    }
    __syncthreads();
    // pass 3: 2 threads per node; pair (2m, 2m+1) shares a wave -> shfl combine
    int m = t >> 1, q = t & 1;
    int gn = (k << CSHIFT) + m;
    if (gn >= N_NODES) return;               // pair-uniform (both lanes same gn)
    unsigned deg = cnt[m];
    unsigned st  = sc[m] - deg + (unsigned)m;
    unsigned h   = (deg >> 1) & ~3u;         // even half multiple of 4
    unsigned lo  = q ? h : 0u, hi = q ? deg : h;
    float b0 = bpos[0], b1 = bpos[1];
    float2 fi = tabI[gn];
    float a0 = fi.x + b0, a1 = fi.y + b1;
    float sn0 = 0.f, sn1 = 0.f, sd0 = 0.f, sd1 = 0.f;
    unsigned e = lo;
    for (; e + 4u <= hi; e += 4u) {
        unsigned j0 = cache[st + e],     j1 = cache[st + e + 1];
        unsigned j2 = cache[st + e + 2], j3 = cache[st + e + 3];
        float4 f0 = tabJ[j0], f1 = tabJ[j1], f2 = tabJ[j2], f3 = tabJ[j3];
        float e00 = __expf(a0 - f0.x), e01 = __expf(a1 - f0.y);
        float e10 = __expf(a0 - f1.x), e11 = __expf(a1 - f1.y);
        float e20 = __expf(a0 - f2.x), e21 = __expf(a1 - f2.y);
        float e30 = __expf(a0 - f3.x), e31 = __expf(a1 - f3.y);
        sn0 += e00 * f0.z + e10 * f1.z + e20 * f2.z + e30 * f3.z;
        sn1 += e01 * f0.w + e11 * f1.w + e21 * f2.w + e31 * f3.w;
        sd0 += e00 + e10 + e20 + e30;
        sd1 += e01 + e11 + e21 + e31;
    }
    for (; e < hi; ++e) {
        unsigned j = cache[st + e];
        float4 fj = tabJ[j];
        float e0 = __expf(a0 - fj.x), e1 = __expf(a1 - fj.y);
        sn0 += e0 * fj.z;  sn1 += e1 * fj.w;
        sd0 += e0;         sd1 += e1;
    }
    // combine pair partials (lanes 2m <-> 2m+1, same wave)
    sn0 += __shfl_xor(sn0, 1);
    sn1 += __shfl_xor(sn1, 1);
    sd0 += __shfl_xor(sd0, 1);
    sd1 += __shfl_xor(sd1, 1);
    if (q == 0) {
        float2 p = pvec[gn];
        float o0 = (sn0 + (p.x + b0) * sd0) / (sd0 + 1e-16f);
        float o1 = (sn1 + (p.y + b1) * sd1) / (sd1 + 1e-16f);
        out[gn] = make_float2(o0, o1);
    }
}

extern "C" void kernel_launch(void* const* d_in, const int* in_sizes, int n_in,
                              void* d_out, int out_size, void* d_ws, size_t ws_size,
                              hipStream_t stream) {
    const float* x    = (const float*)d_in[0];
    const int*   idx  = (const int*)d_in[1];   // (2, E) flat: [0..E)=i, [E..2E)=j
    const float* Wlin = (const float*)d_in[2];
    const float* Wsrc = (const float*)d_in[3];
    const float* Wdst = (const float*)d_in[4];
    const float* Wpos = (const float*)d_in[5];
    const float* bpos = (const float*)d_in[6];
    float* out = (float*)d_out;

    char* ws = (char*)d_ws;
    size_t off = 0;
    float4* tabJ = (float4*)(ws + off); off += (size_t)N_NODES * 16;
    float2* tabI = (float2*)(ws + off); off += (size_t)N_NODES * 8;
    float2* pvec = (float2*)(ws + off); off += (size_t)N_NODES * 8;
    unsigned* packed = (unsigned*)(ws + off); off += ((size_t)N_EDGES + 4u * NCOARSE) * 4;
    unsigned* hist   = (unsigned*)(ws + off); off += (size_t)NBLK * NCOARSE * 4;
    unsigned* totals = (unsigned*)(ws + off); off += (size_t)NCOARSE * 4;
    unsigned* base   = (unsigned*)(ws + off); off += (size_t)NCOARSE * 4;

    node_prep<<<(N_NODES + 255) / 256, 256, 0, stream>>>(x, Wlin, Wsrc, Wdst, Wpos,
                                                         tabI, tabJ, pvec);
    hist_kernel<<<NBLK, 512, 0, stream>>>(idx, hist);
    colscan_kernel<<<NCOARSE, 512, 0, stream>>>(hist, totals);
    basescan_kernel<<<1, 512, 0, stream>>>(totals, base);
    scatter_kernel<<<NBLK, 512, 0, stream>>>(idx, hist, base, packed);
    bucket_agg_kernel<<<NCOARSE, 512, 0, stream>>>(packed, base, totals,
                                                   tabI, tabJ, pvec, bpos,
                                                   (float2*)out);
}

// Round 13
// 183.349 us; speedup vs baseline: 1.1552x; 1.1552x over previous
//
#include <hip/hip_runtime.h>

#define N_NODES 200000
#define N_EDGES 6400000
#define IN_DIM 15
#define POS_DIM 4

#define CSHIFT 8
#define CMASK 255
#define CW 256                                      // nodes per bucket
#define NCOARSE ((N_NODES + CW - 1) >> CSHIFT)      // 782
#define CHUNK 8192                                  // edges per hist/scatter block
#define NBLK ((N_EDGES + CHUNK - 1) / CHUNK)        // 782 (last block 2048 edges)
#define CAP 9216                                    // max bucket edges in LDS (+11 sigma)

typedef unsigned uv4 __attribute__((ext_vector_type(4)));

// ---------------- Pass A: per-node precompute ----------------
__global__ void node_prep(const float* __restrict__ x,
                          const float* __restrict__ Wlin,
                          const float* __restrict__ Wsrc,
                          const float* __restrict__ Wdst,
                          const float* __restrict__ Wpos,
                          float2* __restrict__ tabI,
                          float4* __restrict__ tabJ,
                          float2* __restrict__ pvec)
{
    int n = blockIdx.x * blockDim.x + threadIdx.x;
    if (n >= N_NODES) return;
    const float* xp = x + (long)n * IN_DIM;
    float xv[IN_DIM];
#pragma unroll
    for (int k = 0; k < IN_DIM; ++k) xv[k] = xp[k];

    float p0 = 0.f, p1 = 0.f;
#pragma unroll
    for (int k = 0; k < POS_DIM; ++k) {
        p0 += Wpos[k] * xv[k];
        p1 += Wpos[POS_DIM + k] * xv[k];
    }
    float v0 = 0.f, v1 = 0.f, as0 = 0.f, as1 = 0.f, ad0 = 0.f, ad1 = 0.f;
#pragma unroll
    for (int k = 0; k < IN_DIM; ++k) {
        float xk = xv[k];
        v0  += Wlin[k] * xk;           v1  += Wlin[IN_DIM + k] * xk;
        as0 += Wsrc[k] * xk;           as1 += Wsrc[IN_DIM + k] * xk;
        ad0 += Wdst[k] * xk;           ad1 += Wdst[IN_DIM + k] * xk;
    }
    tabI[n] = make_float2(ad0 + p0, ad1 + p1);
    tabJ[n] = make_float4(as0 + p0, as1 + p1, v0 - p0, v1 - p1);
    pvec[n] = make_float2(p0, p1);
}

// ---------------- K1: per-block bucket histogram (512 threads) --------------
__global__ void hist_kernel(const int* __restrict__ idx,
                            unsigned* __restrict__ hist)   // [NBLK][NCOARSE]
{
    __shared__ unsigned h[NCOARSE];
    for (int t = threadIdx.x; t < NCOARSE; t += blockDim.x) h[t] = 0u;
    __syncthreads();
    long s0 = (long)blockIdx.x * CHUNK;
    int end = (int)min((long)CHUNK, (long)N_EDGES - s0);   // always %2048==0
    for (int t = threadIdx.x * 4; t < end; t += 2048) {
        int4 iv = *(const int4*)(idx + s0 + t);
        atomicAdd(&h[iv.x >> CSHIFT], 1u);
        atomicAdd(&h[iv.y >> CSHIFT], 1u);
        atomicAdd(&h[iv.z >> CSHIFT], 1u);
        atomicAdd(&h[iv.w >> CSHIFT], 1u);
    }
    __syncthreads();
    for (int t = threadIdx.x; t < NCOARSE; t += blockDim.x)
        hist[(unsigned)blockIdx.x * NCOARSE + t] = h[t];
}

// ---------------- K2: exclusive scan down each bucket column (782 rows) -----
__global__ void colscan_kernel(unsigned* __restrict__ hist,
                               unsigned* __restrict__ totals)
{
    __shared__ unsigned s[1024];
    int k = blockIdx.x;                      // 782 columns
    int t = threadIdx.x;                     // 512 threads, 2 elems/thread
    int e0 = t, e1 = t + 512;
    unsigned v0 = (e0 < NBLK) ? hist[(unsigned)e0 * NCOARSE + k] : 0u;
    unsigned v1 = (e1 < NBLK) ? hist[(unsigned)e1 * NCOARSE + k] : 0u;
    s[e0] = v0; s[e1] = v1;
    __syncthreads();
    for (int o = 1; o < 1024; o <<= 1) {
        unsigned a0 = (e0 >= o) ? s[e0 - o] : 0u;
        unsigned a1 = (e1 >= o) ? s[e1 - o] : 0u;
        __syncthreads();
        s[e0] += a0; s[e1] += a1;
        __syncthreads();
    }
    if (e0 < NBLK) hist[(unsigned)e0 * NCOARSE + k] = s[e0] - v0;   // exclusive
    if (e1 < NBLK) hist[(unsigned)e1 * NCOARSE + k] = s[e1] - v1;
    if (e1 == NBLK - 1) totals[k] = s[e1];
}

// ---------------- K3: scan of 4-padded totals -> aligned bases (1024 wide) --
__global__ void basescan_kernel(const unsigned* __restrict__ totals,
                                unsigned* __restrict__ base)
{
    __shared__ unsigned s[1024];
    int t = threadIdx.x;                     // blockDim = 512, 2 elems/thread
    int e0 = t, e1 = t + 512;
    unsigned v0 = (e0 < NCOARSE) ? ((totals[e0] + 3u) & ~3u) : 0u;
    unsigned v1 = (e1 < NCOARSE) ? ((totals[e1] + 3u) & ~3u) : 0u;
    s[e0] = v0; s[e1] = v1;
    __syncthreads();
    for (int off = 1; off < 1024; off <<= 1) {
        unsigned a0 = (e0 >= off) ? s[e0 - off] : 0u;
        unsigned a1 = (e1 >= off) ? s[e1 - off] : 0u;
        __syncthreads();
        s[e0] += a0; s[e1] += a1;
        __syncthreads();
    }
    if (e0 < NCOARSE) base[e0] = s[e0] - v0;   // exclusive, multiple of 4
    if (e1 < NCOARSE) base[e1] = s[e1] - v1;
}

// ---------------- K4: LDS-staged scatter (512 threads, 40 KB LDS) -----------
// Slim tables: counts kept in registers; cnt[] scanned in place; pass-3 run
// boundaries derived from the post-placement invariant cnt[bk]==inclusive[bk].
// 40 KB -> 4 blocks/CU, grid 782 -> full CU coverage.
__global__ void scatter_kernel(const int* __restrict__ idx,
                               const unsigned* __restrict__ hist,
                               const unsigned* __restrict__ base,
                               unsigned* __restrict__ packed)
{
    __shared__ unsigned stage[CHUNK];        // 32 KB
    __shared__ unsigned cnt[1024];           // hist -> exclusive -> inclusive
    __shared__ unsigned gdst[1024];
    int b = blockIdx.x;
    int t = threadIdx.x;                     // 512 threads (8 waves)
    long s0 = (long)b * CHUNK;
    int end = (int)min((long)CHUNK, (long)N_EDGES - s0);   // %2048==0
    cnt[t] = 0u; cnt[t + 512] = 0u;
    __syncthreads();
    // pass 1: local histogram
    for (int e = t * 4; e < end; e += 2048) {
        int4 iv = *(const int4*)(idx + s0 + e);
        atomicAdd(&cnt[iv.x >> CSHIFT], 1u);
        atomicAdd(&cnt[iv.y >> CSHIFT], 1u);
        atomicAdd(&cnt[iv.z >> CSHIFT], 1u);
        atomicAdd(&cnt[iv.w >> CSHIFT], 1u);
    }
    __syncthreads();
    // save own counts, then inclusive scan cnt[] in place (2 elems/thread)
    unsigned c0 = cnt[t], c1 = cnt[t + 512];
    for (int o = 1; o < 1024; o <<= 1) {
        unsigned a0 = (t >= o) ? cnt[t - o] : 0u;
        unsigned a1 = (t + 512 >= o) ? cnt[t + 512 - o] : 0u;
        __syncthreads();
        cnt[t] += a0; cnt[t + 512] += a1;
        __syncthreads();
    }
    unsigned ex0 = cnt[t] - c0;              // exclusive local start
    unsigned ex1 = cnt[t + 512] - c1;
    if (t < NCOARSE) gdst[t] = base[t] + hist[(unsigned)b * NCOARSE + t];
    {
        int u = t + 512;
        if (u < NCOARSE) gdst[u] = base[u] + hist[(unsigned)b * NCOARSE + u];
    }
    __syncthreads();                         // all scan reads done
    cnt[t] = ex0; cnt[t + 512] = ex1;        // cnt becomes cur
    __syncthreads();
    // pass 2: place into LDS stage, bucket-major (restores cnt to inclusive)
    for (int e = t * 4; e < end; e += 2048) {
        int4 iv = *(const int4*)(idx + s0 + e);
        int4 jv = *(const int4*)(idx + N_EDGES + s0 + e);
        unsigned r0 = atomicAdd(&cnt[iv.x >> CSHIFT], 1u);
        unsigned r1 = atomicAdd(&cnt[iv.y >> CSHIFT], 1u);
        unsigned r2 = atomicAdd(&cnt[iv.z >> CSHIFT], 1u);
        unsigned r3 = atomicAdd(&cnt[iv.w >> CSHIFT], 1u);
        stage[r0] = ((unsigned)jv.x << CSHIFT) | (unsigned)(iv.x & CMASK);
        stage[r1] = ((unsigned)jv.y << CSHIFT) | (unsigned)(iv.y & CMASK);
        stage[r2] = ((unsigned)jv.z << CSHIFT) | (unsigned)(iv.z & CMASK);
        stage[r3] = ((unsigned)jv.w << CSHIFT) | (unsigned)(iv.w & CMASK);
    }
    __syncthreads();
    // pass 3: dense copy-out, 16-lane group per bucket run (~10.5 entries)
    int g = t >> 4, l = t & 15;              // 32 groups of 16 lanes
    for (int bk = g; bk < 1024; bk += 32) {
        unsigned st = bk ? cnt[bk - 1] : 0u;   // inclusive[bk-1] == start
        unsigned len = cnt[bk] - st;
        if (len == 0u) continue;
        unsigned gd = gdst[bk];
        for (unsigned e = l; e < len; e += 16u)
            packed[gd + e] = stage[st + e];
    }
}

// ---------------- K5: fused per-bucket sort + aggregate (R12 verbatim) ------
__global__ void bucket_agg_kernel(const unsigned* __restrict__ packed,
                                  const unsigned* __restrict__ base,
                                  const unsigned* __restrict__ totals,
                                  const float2* __restrict__ tabI,
                                  const float4* __restrict__ tabJ,
                                  const float2* __restrict__ pvec,
                                  const float* __restrict__ bpos,
                                  float2* __restrict__ out)
{
    __shared__ unsigned cache[CAP + 256];    // node-major j values (+node stagger)
    __shared__ unsigned cnt[256], sc[256], cur[256];
    int k = blockIdx.x;
    int t = threadIdx.x;                     // 512 threads
    unsigned s = base[k];
    unsigned n = min(totals[k], (unsigned)CAP);   // loud-fail clamp, never hit
    if (t < 256) cnt[t] = 0u;
    __syncthreads();
    // pass 1: histogram of low 8 bits
    for (unsigned e = 4u * t; e < n; e += 2048u) {
        uv4 p = *(const uv4*)(packed + s + e);   // 4-pad -> aligned over-read safe
        atomicAdd(&cnt[p.x & CMASK], 1u);
        if (e + 1 < n) atomicAdd(&cnt[p.y & CMASK], 1u);
        if (e + 2 < n) atomicAdd(&cnt[p.z & CMASK], 1u);
        if (e + 3 < n) atomicAdd(&cnt[p.w & CMASK], 1u);
    }
    __syncthreads();
    // inclusive scan over 256 (t<256 active, barriers uniform)
    if (t < 256) sc[t] = cnt[t];
    __syncthreads();
    for (int o = 1; o < 256; o <<= 1) {
        unsigned a = 0u;
        if (t < 256 && t >= o) a = sc[t - o];
        __syncthreads();
        if (t < 256) sc[t] += a;
        __syncthreads();
    }
    if (t < 256) cur[t] = sc[t] - cnt[t] + (unsigned)t;   // start (+stagger)
    __syncthreads();
    // pass 2: place bare j into LDS, node-major
    for (unsigned e = 4u * t; e < n; e += 2048u) {
        uv4 p = __builtin_nontemporal_load((const uv4*)(packed + s + e));
        { unsigned pos = atomicAdd(&cur[p.x & CMASK], 1u); cache[pos] = p.x >> CSHIFT; }
        if (e + 1 < n) { unsigned pos = atomicAdd(&cur[p.y & CMASK], 1u); cache[pos] = p.y >> CSHIFT; }
        if (e + 2 < n) { unsigned pos = atomicAdd(&cur[p.z & CMASK], 1u); cache[pos] = p.z >> CSHIFT; }
        if (e + 3 < n) { unsigned pos = atomicAdd(&cur[p.w & CMASK], 1u); cache[pos] = p.w >> CSHIFT; }
    }
    __syncthreads();
    // pass 3: 2 threads per node; pair (2m, 2m+1) shares a wave -> shfl combine
    int m = t >> 1, q = t & 1;
    int gn = (k << CSHIFT) + m;
    if (gn >= N_NODES) return;               // pair-uniform (both lanes same gn)
    unsigned deg = cnt[m];
    unsigned st  = sc[m] - deg + (unsigned)m;
    unsigned h   = (deg >> 1) & ~3u;         // even half multiple of 4
    unsigned lo  = q ? h : 0u, hi = q ? deg : h;
    float b0 = bpos[0], b1 = bpos[1];
    float2 fi = tabI[gn];
    float a0 = fi.x + b0, a1 = fi.y + b1;
    float sn0 = 0.f, sn1 = 0.f, sd0 = 0.f, sd1 = 0.f;
    unsigned e = lo;
    for (; e + 4u <= hi; e += 4u) {
        unsigned j0 = cache[st + e],     j1 = cache[st + e + 1];
        unsigned j2 = cache[st + e + 2], j3 = cache[st + e + 3];
        float4 f0 = tabJ[j0], f1 = tabJ[j1], f2 = tabJ[j2], f3 = tabJ[j3];
        float e00 = __expf(a0 - f0.x), e01 = __expf(a1 - f0.y);
        float e10 = __expf(a0 - f1.x), e11 = __expf(a1 - f1.y);
        float e20 = __expf(a0 - f2.x), e21 = __expf(a1 - f2.y);
        float e30 = __expf(a0 - f3.x), e31 = __expf(a1 - f3.y);
        sn0 += e00 * f0.z + e10 * f1.z + e20 * f2.z + e30 * f3.z;
        sn1 += e01 * f0.w + e11 * f1.w + e21 * f2.w + e31 * f3.w;
        sd0 += e00 + e10 + e20 + e30;
        sd1 += e01 + e11 + e21 + e31;
    }
    for (; e < hi; ++e) {
        unsigned j = cache[st + e];
        float4 fj = tabJ[j];
        float e0 = __expf(a0 - fj.x), e1 = __expf(a1 - fj.y);
        sn0 += e0 * fj.z;  sn1 += e1 * fj.w;
        sd0 += e0;         sd1 += e1;
    }
    // combine pair partials (lanes 2m <-> 2m+1, same wave)
    sn0 += __shfl_xor(sn0, 1);
    sn1 += __shfl_xor(sn1, 1);
    sd0 += __shfl_xor(sd0, 1);
    sd1 += __shfl_xor(sd1, 1);
    if (q == 0) {
        float2 p = pvec[gn];
        float o0 = (sn0 + (p.x + b0) * sd0) / (sd0 + 1e-16f);
        float o1 = (sn1 + (p.y + b1) * sd1) / (sd1 + 1e-16f);
        out[gn] = make_float2(o0, o1);
    }
}

extern "C" void kernel_launch(void* const* d_in, const int* in_sizes, int n_in,
                              void* d_out, int out_size, void* d_ws, size_t ws_size,
                              hipStream_t stream) {
    const float* x    = (const float*)d_in[0];
    const int*   idx  = (const int*)d_in[1];   // (2, E) flat: [0..E)=i, [E..2E)=j
    const float* Wlin = (const float*)d_in[2];
    const float* Wsrc = (const float*)d_in[3];
    const float* Wdst = (const float*)d_in[4];
    const float* Wpos = (const float*)d_in[5];
    const float* bpos = (const float*)d_in[6];
    float* out = (float*)d_out;

    char* ws = (char*)d_ws;
    size_t off = 0;
    float4* tabJ = (float4*)(ws + off); off += (size_t)N_NODES * 16;
    float2* tabI = (float2*)(ws + off); off += (size_t)N_NODES * 8;
    float2* pvec = (float2*)(ws + off); off += (size_t)N_NODES * 8;
    unsigned* packed = (unsigned*)(ws + off); off += ((size_t)N_EDGES + 4u * NCOARSE) * 4;
    unsigned* hist   = (unsigned*)(ws + off); off += (size_t)NBLK * NCOARSE * 4;
    unsigned* totals = (unsigned*)(ws + off); off += (size_t)NCOARSE * 4;
    unsigned* base   = (unsigned*)(ws + off); off += (size_t)NCOARSE * 4;

    node_prep<<<(N_NODES + 255) / 256, 256, 0, stream>>>(x, Wlin, Wsrc, Wdst, Wpos,
                                                         tabI, tabJ, pvec);
    hist_kernel<<<NBLK, 512, 0, stream>>>(idx, hist);
    colscan_kernel<<<NCOARSE, 512, 0, stream>>>(hist, totals);
    basescan_kernel<<<1, 512, 0, stream>>>(totals, base);
    scatter_kernel<<<NBLK, 512, 0, stream>>>(idx, hist, base, packed);
    bucket_agg_kernel<<<NCOARSE, 512, 0, stream>>>(packed, base, totals,
                                                   tabI, tabJ, pvec, bpos,
                                                   (float2*)out);
}